// Round 8
// baseline (298.372 us; speedup 1.0000x reference)
//
#include <hip/hip_runtime.h>
#include <hip/hip_bf16.h>

// Problem constants (from reference): B=512, T=64, A=32, H=512, E=32
#define B_ 512
#define T_ 64
#define A_ 32
#define H_ 512
#define E_ 32
#define MAX_TASKS 272   // sum_e ceil(cnt_e/2) <= 256 + 16
#define CAP_ 168        // itemlist capacity per XCD class
#define GRID_ (8 * CAP_)

typedef unsigned short u16;
typedef unsigned int u32;
typedef __attribute__((ext_vector_type(8))) short short8;   // 8 bf16 (MFMA A/B frag)
typedef __attribute__((ext_vector_type(4))) float floatx4;  // MFMA C/D frag

static __device__ __forceinline__ u16 f2bf(float f) {
    u32 u = __builtin_bit_cast(u32, f);
    u += 0x7fffu + ((u >> 16) & 1u);   // RNE
    return (u16)(u >> 16);
}

// async global->LDS, 16B per lane; LDS dest is wave-uniform base (HW adds
// lane*16). Swizzle must be applied on the GLOBAL address per lane.
static __device__ __forceinline__ void gl2lds16(const u16* g, u16* l) {
    __builtin_amdgcn_global_load_lds(
        (const __attribute__((address_space(1))) void*)g,
        (__attribute__((address_space(3))) void*)l, 16, 0, 0);
}

// ---------------------------------------------------------------------------
// Launch 1 (FUSED): blocks [0,512) = per-sample embed work; block 512 = the
// grouping block. Embed: GEMM1 (K=32, fp32 VALU, 1 col/thread) -> bf16
// a_emb; tau table tauG[s][512] (2 trig/thread).
// ---------------------------------------------------------------------------
__global__ __launch_bounds__(512) void embed_group_kernel(
        const float* __restrict__ actions, const float* __restrict__ timesteps,
        const int* __restrict__ cat_ids, const float* __restrict__ W1,
        const float* __restrict__ b1,
        u16* __restrict__ a_emb, float* __restrict__ tauG,
        int* __restrict__ sample_list, int4* __restrict__ tasks,
        int* __restrict__ itemlist, int* __restrict__ eoff_g,
        int* __restrict__ ecnt_g) {
    int tid = threadIdx.x;

    if (blockIdx.x == B_) {
        // ------------------- grouping block (uniform branch) -------------------
        __shared__ int cnt[E_], off[E_], cur[E_], toff[E_], jc[8];
        __shared__ int total, fb;
        if (tid < E_) { cnt[tid] = 0; cur[tid] = 0; }
        __syncthreads();
        int e = cat_ids[tid];               // tid in [0,512) == B_
        atomicAdd(&cnt[e], 1);
        __syncthreads();
        if (tid == 0) {
            int run = 0, trun = 0;
            for (int i = 0; i < E_; i++) {
                off[i] = run;  run += cnt[i];
                toff[i] = trun; trun += (cnt[i] + 1) >> 1;
            }
            total = trun;
        }
        __syncthreads();
        if (tid < E_) {
            int c = cnt[tid], o = off[tid], to = toff[tid];
            eoff_g[tid] = o;
            ecnt_g[tid] = c;
            for (int j = 0; j < c; j += 2)
                tasks[to++] = make_int4(tid, o + j, (c - j >= 2) ? 2 : 1, 0);
        }
        if (tid < 8) {
            int J = 0;
            for (int cc = 0; cc < 4; cc++)
                J += 4 * ((cnt[tid + 8 * cc] + 1) >> 1);
            jc[tid] = J;
        }
        __syncthreads();
        if (tid == 0) {
            int f = 0;
            for (int x = 0; x < 8; x++) if (jc[x] > CAP_) f = 1;
            fb = f;
        }
        __syncthreads();
        if (!fb) {
            if (tid < 8) {
                int j = 0;
                for (int cc = 0; cc < 4; cc++) {
                    int ee = tid + 8 * cc;
                    int nt = (cnt[ee] + 1) >> 1, t0 = toff[ee];
                    for (int t = t0; t < t0 + nt; t++)
                        for (int nb = 0; nb < 4; nb++) {
                            itemlist[tid + 8 * j] = (t << 2) | nb;
                            j++;
                        }
                }
                for (; j < CAP_; j++) itemlist[tid + 8 * j] = -1;
            }
        } else {
            for (int f = tid; f < GRID_; f += 512)
                itemlist[f] = (f < 4 * total) ? f : -1;
        }
        int p = atomicAdd(&cur[e], 1);
        sample_list[off[e] + p] = tid;
        return;
    }

    // ---------------------------- embed block ----------------------------
    int b = blockIdx.x;
    int e = cat_ids[b];
    {
        float tval = timesteps[b];
        int kk = tid & 255;
        float freq = expf(-9.210340371976184f * (float)kk * (1.0f / 256.0f));
        float ang = tval * freq;
        tauG[(size_t)b * H_ + tid] = (tid < 256) ? sinf(ang) : cosf(ang);
    }

    __shared__ float act[T_ * A_];
    const float* asrc = actions + (size_t)b * T_ * A_;
    for (int i = tid; i < T_ * A_; i += 512) act[i] = asrc[i];
    __syncthreads();

    const float* w1 = W1 + (size_t)e * A_ * H_;
    float wcol[A_];
#pragma unroll
    for (int k = 0; k < A_; k++) wcol[k] = w1[k * H_ + tid];
    float bb = b1[e * H_ + tid];
    u16* orow = a_emb + (size_t)b * T_ * H_;
    for (int tt = 0; tt < T_; tt++) {
        float acc = bb;
#pragma unroll
        for (int k = 0; k < A_; k++)
            acc = fmaf(act[tt * A_ + k], wcol[k], acc);   // LDS broadcast
        orow[tt * H_ + tid] = f2bf(acc);
    }
}

// ---------------------------------------------------------------------------
// convert-transpose core (64-k granularity, RESTORED from round 4): W
// [e][srcK][512] f32 rows [k0,k0+64) -> Wt [e][512][dstK] bf16. Each thread
// writes a FULL 128B line of its Wt row (8 back-to-back 16B stores that L2
// merges). Round 6-7's 32-k variant split every 128B line across two blocks
// (potentially two XCDs' L2s) -> partial-line HBM writes with RMW.
// Reads: 64 independent 4B strided loads, 256B/wave-instr coalesced.
// ---------------------------------------------------------------------------
static __device__ __forceinline__ void ct_block64(
        const float* __restrict__ W, u16* __restrict__ Wt,
        int srcK, int dstK, int e, int k0, int n) {
    const float* src = W + ((size_t)e * srcK + k0) * H_ + n;
    short8 out[8];
#pragma unroll
    for (int j = 0; j < 64; j++)
        out[j >> 3][j & 7] = (short)f2bf(src[(size_t)j * H_]);
    u16* dst = Wt + ((size_t)e * H_ + n) * dstK + k0;
#pragma unroll
    for (int c = 0; c < 8; c++) *(short8*)(dst + c * 8) = out[c];
}

// ---------------------------------------------------------------------------
// Launch 3: ct2 (blocks [0,512)) + ct3 (blocks [512,1024)). Split from the
// tau work this round so rocprof attributes prep's cost per half.
// ---------------------------------------------------------------------------
__global__ __launch_bounds__(256) void ctw_kernel(
        const float* __restrict__ W2, const float* __restrict__ W3,
        u16* __restrict__ Wt2a, u16* __restrict__ Wt3) {
    int tid = threadIdx.x, bid = blockIdx.x;
    if (bid < 512) {
        int e = bid >> 4, sub = bid & 15;
        ct_block64(W2, Wt2a, 2 * H_, H_, e, (sub & 7) * 64,
                   (sub >> 3) * 256 + tid);
    } else {
        int local = bid - 512;
        int e = local >> 4, sub = local & 15;
        ct_block64(W3, Wt3, H_, H_, e, (sub & 7) * 64,
                   (sub >> 3) * 256 + tid);
    }
}

// ---------------------------------------------------------------------------
// Launch 2: tau_bias standalone (512 blocks), sample-parallel, no atomics.
// Block = (4-sample group g, 128-col quarter q). Wave = 1 sample; lanes
// 0-31 own 4 cols (float4 W loads, 16B/lane), lanes 32-63 take k in
// [256,512); one __shfl_xor(32) fold. bias2s[s][n] = sum + b2[e][n], float4
// stores. Chunked XCD map keeps each expert's W2b slice hot in one L2.
// ISOLATED this round: if it shows >>15us with idle pipes, the 4x intra-
// block redundant W reads (4 waves read identical W addresses) is the
// cost -> next fix is wave-cooperative W reads.
// ---------------------------------------------------------------------------
__global__ __launch_bounds__(256) void tau_bias_kernel(
        const float* __restrict__ W2, const float* __restrict__ tauG,
        const float* __restrict__ b2,
        const int* __restrict__ cat_ids, const int* __restrict__ sample_list,
        float* __restrict__ bias2s) {
    int tid = threadIdx.x;
    int bid = blockIdx.x;

    __shared__ float tauLds[4][512];   // 8 KB

    int xcd = bid & 7, jj = bid >> 3;
    int u = xcd * 64 + jj;             // chunked: XCD x owns u in [64x,64x+64)
    int g = u >> 2, q = u & 3;         // sample group (4 samples), col quarter

    // stage the 4 tau rows (f32, coalesced 2KB rows)
    for (int i = tid; i < 4 * 512; i += 256) {
        int sl = i >> 9, k = i & 511;
        tauLds[sl][k] = tauG[(size_t)sample_list[g * 4 + sl] * H_ + k];
    }
    __syncthreads();

    int wv = tid >> 6, lane = tid & 63;
    int l = lane & 31, kh = lane >> 5;          // col lane, k-half
    int s = sample_list[g * 4 + wv];
    int e = cat_ids[s];
    const float* wb = W2 + ((size_t)e * 1024 + 512 + kh * 256) * H_
                      + q * 128 + l * 4;
    const float* tp = &tauLds[wv][kh * 256];

    float4 acc = {0.f, 0.f, 0.f, 0.f};
#pragma unroll 2
    for (int k4 = 0; k4 < 256; k4 += 4) {
        float4 t4 = *(const float4*)&tp[k4];                 // b128 broadcast
        float4 w0 = *(const float4*)(wb + (size_t)(k4 + 0) * H_);
        float4 w1 = *(const float4*)(wb + (size_t)(k4 + 1) * H_);
        float4 w2 = *(const float4*)(wb + (size_t)(k4 + 2) * H_);
        float4 w3 = *(const float4*)(wb + (size_t)(k4 + 3) * H_);
        acc.x = fmaf(t4.x, w0.x, acc.x); acc.y = fmaf(t4.x, w0.y, acc.y);
        acc.z = fmaf(t4.x, w0.z, acc.z); acc.w = fmaf(t4.x, w0.w, acc.w);
        acc.x = fmaf(t4.y, w1.x, acc.x); acc.y = fmaf(t4.y, w1.y, acc.y);
        acc.z = fmaf(t4.y, w1.z, acc.z); acc.w = fmaf(t4.y, w1.w, acc.w);
        acc.x = fmaf(t4.z, w2.x, acc.x); acc.y = fmaf(t4.z, w2.y, acc.y);
        acc.z = fmaf(t4.z, w2.z, acc.z); acc.w = fmaf(t4.z, w2.w, acc.w);
        acc.x = fmaf(t4.w, w3.x, acc.x); acc.y = fmaf(t4.w, w3.y, acc.y);
        acc.z = fmaf(t4.w, w3.z, acc.z); acc.w = fmaf(t4.w, w3.w, acc.w);
    }

    // fold the two k-halves: lanes l and l+32 share (sample, cols)
    acc.x += __shfl_xor(acc.x, 32, 64);
    acc.y += __shfl_xor(acc.y, 32, 64);
    acc.z += __shfl_xor(acc.z, 32, 64);
    acc.w += __shfl_xor(acc.w, 32, 64);

    if (kh == 0) {
        int n = q * 128 + l * 4;
        float4 bv = *(const float4*)(b2 + (size_t)e * H_ + n);
        float4 outv = {acc.x + bv.x, acc.y + bv.y, acc.z + bv.z, acc.w + bv.w};
        *(float4*)&bias2s[(size_t)s * H_ + n] = outv;   // coalesced 512B/wave
    }
}

// ---------------------------------------------------------------------------
// Kernels GEMM2/GEMM3: expert-grouped MFMA GEMM, K=512 (tau folded out).
// Block: 256 threads (4 waves), tile M=128 (2 samples) x N=128, BK=64.
// True 2-deep pipeline (T3+T4): raw s_barrier + counted vmcnt(8).
// Per iter: compute(t) -> s_barrier (all waves done reading buf[t&1]) ->
// stage(t+2) into buf[t&1] -> s_waitcnt vmcnt(8) (waits ONLY t+1's 8 loads;
// t+2's 8 stay in flight across the barrier) -> s_barrier -> next iter.
// Swizzle: 16B chunk c of row r at slot c^(r&7), applied on the global
// address side (gl2lds dest must be linear); frag reads conflict-free.
// ---------------------------------------------------------------------------
template <int DIN, bool PSBIAS, bool DO_SWISH, bool OUT_BF16>
__global__ __launch_bounds__(256, 2) void moe_gemm(
        const u16* __restrict__ xsrc, const u16* __restrict__ Wt,
        const float* __restrict__ bias,
        const int* __restrict__ sample_list, const int4* __restrict__ tasks,
        const int* __restrict__ itemlist, void* __restrict__ outp) {
    int item = itemlist[blockIdx.x];
    if (item < 0) return;
    int4 task = tasks[item >> 2];
    int nb = item & 3;
    int ns = task.z;
    int e = task.x;
    int s0 = sample_list[task.y];
    int s1 = (ns > 1) ? sample_list[task.y + 1] : s0;  // dup reads, masked store
    int n0 = nb * 128;

    int tid = threadIdx.x;
    int lane = tid & 63, wv = tid >> 6;          // 4 waves
    int wr = wv >> 1, wc = wv & 1;               // 2x2 wave grid
    int quad = lane >> 4, c15 = lane & 15;
    int r8 = lane >> 3, cg = lane & 7;           // staging: row-in-group, chunk

    __shared__ __align__(16) u16 xs[2][128 * 64];   // 2 x 16 KB
    __shared__ __align__(16) u16 wt[2][128 * 64];   // 2 x 16 KB

    floatx4 acc[4][4];
    floatx4 zero4 = {0.f, 0.f, 0.f, 0.f};
#pragma unroll
    for (int i = 0; i < 4; i++)
#pragma unroll
        for (int j = 0; j < 4; j++) acc[i][j] = zero4;

    const u16* wbase = Wt + (size_t)(e * H_ + n0) * DIN;
    int kc_sw = (cg ^ r8) * 8;                   // swizzled global k-offset

    auto stage = [&](int b, int k0) {            // 8 loads per wave
#pragma unroll
        for (int h = 0; h < 4; h++) {
            int rbase = h * 32 + wv * 8;         // wave-uniform row-group base
            int s = (h < 2) ? s0 : s1;
            int t = (rbase + r8) & 63;
            gl2lds16(xsrc + ((size_t)s * T_ + t) * H_ + k0 + kc_sw,
                     &xs[b][rbase * 64]);
        }
#pragma unroll
        for (int h = 0; h < 4; h++) {
            int nbase = h * 32 + wv * 8;
            gl2lds16(wbase + (size_t)(nbase + r8) * DIN + k0 + kc_sw,
                     &wt[b][nbase * 64]);
        }
    };

    auto compute = [&](int b) {
#pragma unroll
        for (int kk = 0; kk < 2; kk++) {
            int c = kk * 4 + quad;               // k-chunk index 0..7
            short8 af[4], bfr[4];
#pragma unroll
            for (int i = 0; i < 4; i++) {
                int row = wr * 64 + i * 16 + c15;
                af[i] = *(const short8*)&xs[b][row * 64 + ((c ^ (row & 7)) * 8)];
                int nr = wc * 64 + i * 16 + c15;
                bfr[i] = *(const short8*)&wt[b][nr * 64 + ((c ^ (nr & 7)) * 8)];
            }
#pragma unroll
            for (int mt = 0; mt < 4; mt++)
#pragma unroll
                for (int nt = 0; nt < 4; nt++)
                    acc[mt][nt] = __builtin_amdgcn_mfma_f32_16x16x32_bf16(
                            af[mt], bfr[nt], acc[mt][nt], 0, 0, 0);
        }
    };

    constexpr int KI = DIN / 64;                 // 8 K-iterations
    stage(0, 0);                                 // 8 loads (buf0)
    stage(1, 64);                                // 8 loads (buf1)
    asm volatile("s_waitcnt vmcnt(8)" ::: "memory");  // own buf0 loads done
    __builtin_amdgcn_s_barrier();                // all waves' buf0 done
    __builtin_amdgcn_sched_barrier(0);
#pragma unroll
    for (int t = 0; t < KI; ++t) {
        compute(t & 1);
        if (t + 1 < KI) {
            __builtin_amdgcn_s_barrier();        // all waves done reading buf[t&1]
            __builtin_amdgcn_sched_barrier(0);
            if (t + 2 < KI) {
                stage(t & 1, (t + 2) * 64);      // buf[(t+2)&1] == buf[t&1]
                asm volatile("s_waitcnt vmcnt(8)" ::: "memory"); // t+1 done
            } else {
                asm volatile("s_waitcnt vmcnt(0)" ::: "memory"); // drain last
            }
            __builtin_amdgcn_s_barrier();        // all waves' t+1 loads done
            __builtin_amdgcn_sched_barrier(0);
        }
    }

    // ---- epilogue: C/D layout col=c15, row=quad*4+r; wave-row wr = sample ----
    if (wr >= ns) return;
    int s = (wr == 0) ? s0 : s1;
    const float* bp = PSBIAS ? (bias + (size_t)s * H_)   // per-sample (GEMM2)
                             : (bias + (size_t)e * H_);  // per-expert (GEMM3)
#pragma unroll
    for (int mt = 0; mt < 4; mt++) {
        int tb = mt * 16 + quad * 4;             // t base within sample
#pragma unroll
        for (int nt = 0; nt < 4; nt++) {
            int col = n0 + wc * 64 + nt * 16 + c15;
            float bv = bp[col];
#pragma unroll
            for (int r = 0; r < 4; r++) {
                float v = acc[mt][nt][r] + bv;
                if (DO_SWISH) v = v / (1.0f + expf(-v));   // x*sigmoid(x)
                size_t oidx = ((size_t)s * T_ + tb + r) * H_ + col;
                if (OUT_BF16) ((u16*)outp)[oidx] = f2bf(v);
                else          ((float*)outp)[oidx] = v;
            }
        }
    }
}

// ---------------------------------------------------------------------------
extern "C" void kernel_launch(void* const* d_in, const int* in_sizes, int n_in,
                              void* d_out, int out_size, void* d_ws, size_t ws_size,
                              hipStream_t stream) {
    const float* actions   = (const float*)d_in[0];
    const float* timesteps = (const float*)d_in[1];
    const int*   cat_ids   = (const int*)d_in[2];
    const float* W1 = (const float*)d_in[3];
    const float* b1 = (const float*)d_in[4];
    const float* W2 = (const float*)d_in[5];
    const float* b2 = (const float*)d_in[6];
    const float* W3 = (const float*)d_in[7];
    const float* b3 = (const float*)d_in[8];

    // d_out (64 MiB) is scratch until GEMM3's epilogue:
    //   Wt2a bf16 [0,16MiB) | a_emb bf16 [16,48) | bias2s f32 [48,49) |
    //   tauG f32 [49,50).
    // ws: Wt3 bf16 [0,32MiB slot) | y bf16 [32,64) | meta.
    // GEMM3 reads only ws (+b3) and writes d_out -> no overlap hazard.
    char* ws = (char*)d_ws;
    u16* Wt3   = (u16*)ws;
    u16* y     = (u16*)(ws + (size_t)32 * 1024 * 1024);
    char* meta = ws + (size_t)64 * 1024 * 1024 + 512 * 1024;
    int*  sample_list = (int*)meta;                     // 2 KB
    int4* tasks       = (int4*)(meta + 8192);           // 272*16 B
    int*  itemlist    = (int*)(meta + 16384);           // GRID_*4 B
    int*  eoff        = (int*)(meta + 24576);           // 128 B
    int*  ecnt        = (int*)(meta + 24576 + 128);     // 128 B
    u16*  Wt2a   = (u16*)d_out;
    u16*  a_emb  = (u16*)((char*)d_out + (size_t)16 * 1024 * 1024);
    float* bias2s = (float*)((char*)d_out + (size_t)48 * 1024 * 1024);
    float* tauG   = (float*)((char*)d_out + (size_t)49 * 1024 * 1024);

    // Launch 1: embed (512 blocks) + group (block 512)
    hipLaunchKernelGGL(embed_group_kernel, dim3(B_ + 1), dim3(512), 0, stream,
                       actions, timesteps, cat_ids, W1, b1,
                       a_emb, tauG,
                       sample_list, tasks, itemlist, eoff, ecnt);
    // Launch 2: tau_bias (512 blocks) — isolated for per-dispatch counters
    hipLaunchKernelGGL(tau_bias_kernel, dim3(512), dim3(256), 0, stream,
                       W2, tauG, b2, cat_ids, sample_list, bias2s);
    // Launch 3: ct2+ct3 (1024 blocks, full-line writes)
    hipLaunchKernelGGL(ctw_kernel, dim3(1024), dim3(256), 0, stream,
                       W2, W3, Wt2a, Wt3);
    // Launch 4: GEMM2 (reads d_out scratch, writes y in ws)
    hipLaunchKernelGGL((moe_gemm<H_, true, true, true>), dim3(GRID_),
                       dim3(256), 0, stream,
                       a_emb, Wt2a, bias2s, sample_list, tasks, itemlist,
                       (void*)y);
    // Launch 5: GEMM3 (reads ws, writes d_out)
    hipLaunchKernelGGL((moe_gemm<H_, false, false, false>), dim3(GRID_),
                       dim3(256), 0, stream,
                       y, Wt3, b3, sample_list, tasks, itemlist, d_out);
}

// Round 9
// 281.940 us; speedup vs baseline: 1.0583x; 1.0583x over previous
//
#include <hip/hip_runtime.h>
#include <hip/hip_bf16.h>

// Problem constants (from reference): B=512, T=64, A=32, H=512, E=32
#define B_ 512
#define T_ 64
#define A_ 32
#define H_ 512
#define E_ 32
#define MAX_TASKS 272   // sum_e ceil(cnt_e/2) <= 256 + 16
#define CAP_ 168        // itemlist capacity per XCD class
#define GRID_ (8 * CAP_)

typedef unsigned short u16;
typedef unsigned int u32;
typedef __attribute__((ext_vector_type(8))) short short8;   // 8 bf16 (MFMA A/B frag)
typedef __attribute__((ext_vector_type(4))) float floatx4;  // MFMA C/D frag

static __device__ __forceinline__ u16 f2bf(float f) {
    u32 u = __builtin_bit_cast(u32, f);
    u += 0x7fffu + ((u >> 16) & 1u);   // RNE
    return (u16)(u >> 16);
}

// async global->LDS, 16B per lane; LDS dest is wave-uniform base (HW adds
// lane*16). Swizzle must be applied on the GLOBAL address per lane.
static __device__ __forceinline__ void gl2lds16(const u16* g, u16* l) {
    __builtin_amdgcn_global_load_lds(
        (const __attribute__((address_space(1))) void*)g,
        (__attribute__((address_space(3))) void*)l, 16, 0, 0);
}

// ---------------------------------------------------------------------------
// Launch 1 (FUSED): blocks [0,512) = per-sample embed work; block 512 = the
// grouping block. Embed: GEMM1 (K=32, fp32 VALU, 1 col/thread) -> bf16
// a_emb; tau table tauG[s][512] (2 trig/thread).
// ---------------------------------------------------------------------------
__global__ __launch_bounds__(512) void embed_group_kernel(
        const float* __restrict__ actions, const float* __restrict__ timesteps,
        const int* __restrict__ cat_ids, const float* __restrict__ W1,
        const float* __restrict__ b1,
        u16* __restrict__ a_emb, float* __restrict__ tauG,
        int* __restrict__ sample_list, int4* __restrict__ tasks,
        int* __restrict__ itemlist, int* __restrict__ eoff_g,
        int* __restrict__ ecnt_g) {
    int tid = threadIdx.x;

    if (blockIdx.x == B_) {
        // ------------------- grouping block (uniform branch) -------------------
        __shared__ int cnt[E_], off[E_], cur[E_], toff[E_], jc[8];
        __shared__ int total, fb;
        if (tid < E_) { cnt[tid] = 0; cur[tid] = 0; }
        __syncthreads();
        int e = cat_ids[tid];               // tid in [0,512) == B_
        atomicAdd(&cnt[e], 1);
        __syncthreads();
        if (tid == 0) {
            int run = 0, trun = 0;
            for (int i = 0; i < E_; i++) {
                off[i] = run;  run += cnt[i];
                toff[i] = trun; trun += (cnt[i] + 1) >> 1;
            }
            total = trun;
        }
        __syncthreads();
        if (tid < E_) {
            int c = cnt[tid], o = off[tid], to = toff[tid];
            eoff_g[tid] = o;
            ecnt_g[tid] = c;
            for (int j = 0; j < c; j += 2)
                tasks[to++] = make_int4(tid, o + j, (c - j >= 2) ? 2 : 1, 0);
        }
        if (tid < 8) {
            int J = 0;
            for (int cc = 0; cc < 4; cc++)
                J += 4 * ((cnt[tid + 8 * cc] + 1) >> 1);
            jc[tid] = J;
        }
        __syncthreads();
        if (tid == 0) {
            int f = 0;
            for (int x = 0; x < 8; x++) if (jc[x] > CAP_) f = 1;
            fb = f;
        }
        __syncthreads();
        if (!fb) {
            if (tid < 8) {
                int j = 0;
                for (int cc = 0; cc < 4; cc++) {
                    int ee = tid + 8 * cc;
                    int nt = (cnt[ee] + 1) >> 1, t0 = toff[ee];
                    for (int t = t0; t < t0 + nt; t++)
                        for (int nb = 0; nb < 4; nb++) {
                            itemlist[tid + 8 * j] = (t << 2) | nb;
                            j++;
                        }
                }
                for (; j < CAP_; j++) itemlist[tid + 8 * j] = -1;
            }
        } else {
            for (int f = tid; f < GRID_; f += 512)
                itemlist[f] = (f < 4 * total) ? f : -1;
        }
        int p = atomicAdd(&cur[e], 1);
        sample_list[off[e] + p] = tid;
        return;
    }

    // ---------------------------- embed block ----------------------------
    int b = blockIdx.x;
    int e = cat_ids[b];
    {
        float tval = timesteps[b];
        int kk = tid & 255;
        float freq = expf(-9.210340371976184f * (float)kk * (1.0f / 256.0f));
        float ang = tval * freq;
        tauG[(size_t)b * H_ + tid] = (tid < 256) ? sinf(ang) : cosf(ang);
    }

    __shared__ float act[T_ * A_];
    const float* asrc = actions + (size_t)b * T_ * A_;
    for (int i = tid; i < T_ * A_; i += 512) act[i] = asrc[i];
    __syncthreads();

    const float* w1 = W1 + (size_t)e * A_ * H_;
    float wcol[A_];
#pragma unroll
    for (int k = 0; k < A_; k++) wcol[k] = w1[k * H_ + tid];
    float bb = b1[e * H_ + tid];
    u16* orow = a_emb + (size_t)b * T_ * H_;
    for (int tt = 0; tt < T_; tt++) {
        float acc = bb;
#pragma unroll
        for (int k = 0; k < A_; k++)
            acc = fmaf(act[tt * A_ + k], wcol[k], acc);   // LDS broadcast
        orow[tt * H_ + tid] = f2bf(acc);
    }
}

// ---------------------------------------------------------------------------
// Launch 3: ct2 (blocks [0,512)) + ct3 (blocks [512,1024)).
// Round-8 post-mortem: old ct did 64 scalar strided 4B loads/thread at
// VGPR=36 -> compiler batched load->cvt->pack with waitcnt every few loads,
// exposing ~600cy latency per batch (VALUBusy 2.4%, 1.35 TB/s, 55.7us).
// NEW: LDS-staged transpose, per block one 64k x 256n tile:
//  Phase A: thread = (16k group, float4 n-lane): 16 float4 loads (1KB/wave
//    coalesced), cvt to bf16, 8B ds_write_b64 into lt[k][n] (2 lanes/bank,
//    free). Phase B: thread = one n column: 64 ds_read_u16 down the column
//    (per-instr lanes span 64 n -> 2 lanes/bank, free), pack 8 short8,
//    write ONE FULL 128B line of the Wt row. One barrier. 32KB LDS.
// ---------------------------------------------------------------------------
static __device__ __forceinline__ void ct_tile_lds(
        const float* __restrict__ W, u16* __restrict__ Wt,
        int srcK, int dstK, int e, int k0, int n0,
        u16 (*lt)[256], int tid) {
    int nl = (tid & 63) * 4;      // n within tile (float4 lane)
    int kg = tid >> 6;            // k-group: 16 rows each
    const float* src = W + ((size_t)e * srcK + k0 + kg * 16) * H_ + n0 + nl;
#pragma unroll
    for (int j = 0; j < 16; j++) {
        float4 v = *(const float4*)(src + (size_t)j * H_);   // coalesced 1KB
        u32 lo = (u32)f2bf(v.x) | ((u32)f2bf(v.y) << 16);
        u32 hi = (u32)f2bf(v.z) | ((u32)f2bf(v.w) << 16);
        *(uint2*)&lt[kg * 16 + j][nl] = make_uint2(lo, hi);  // ds_write_b64
    }
    __syncthreads();
    short8 out[8];
#pragma unroll
    for (int k = 0; k < 64; k++)
        out[k >> 3][k & 7] = (short)lt[k][tid];              // 2-way, free
    u16* dst = Wt + ((size_t)e * H_ + n0 + tid) * dstK + k0;
#pragma unroll
    for (int c = 0; c < 8; c++) *(short8*)(dst + c * 8) = out[c];  // 128B line
}

__global__ __launch_bounds__(256) void ctw_kernel(
        const float* __restrict__ W2, const float* __restrict__ W3,
        u16* __restrict__ Wt2a, u16* __restrict__ Wt3) {
    __shared__ u16 lt[64][256];   // 32 KB
    int tid = threadIdx.x, bid = blockIdx.x;
    if (bid < 512) {
        int e = bid >> 4, sub = bid & 15;
        ct_tile_lds(W2, Wt2a, 2 * H_, H_, e, (sub & 7) * 64,
                    (sub >> 3) * 256, lt, tid);
    } else {
        int local = bid - 512;
        int e = local >> 4, sub = local & 15;
        ct_tile_lds(W3, Wt3, H_, H_, e, (sub & 7) * 64,
                    (sub >> 3) * 256, lt, tid);
    }
}

// ---------------------------------------------------------------------------
// Launch 2: tau_bias standalone (512 blocks), sample-parallel, no atomics.
// Block = (4-sample group g, 128-col quarter q). Wave = 1 sample; lanes
// 0-31 own 4 cols (float4 W loads, 16B/lane), lanes 32-63 take k in
// [256,512); one __shfl_xor(32) fold. bias2s[s][n] = sum + b2[e][n], float4
// stores. Chunked XCD map keeps each expert's W2b slice hot in one L2.
// Kept isolated so its per-dispatch counters surface next round.
// ---------------------------------------------------------------------------
__global__ __launch_bounds__(256) void tau_bias_kernel(
        const float* __restrict__ W2, const float* __restrict__ tauG,
        const float* __restrict__ b2,
        const int* __restrict__ cat_ids, const int* __restrict__ sample_list,
        float* __restrict__ bias2s) {
    int tid = threadIdx.x;
    int bid = blockIdx.x;

    __shared__ float tauLds[4][512];   // 8 KB

    int xcd = bid & 7, jj = bid >> 3;
    int u = xcd * 64 + jj;             // chunked: XCD x owns u in [64x,64x+64)
    int g = u >> 2, q = u & 3;         // sample group (4 samples), col quarter

    // stage the 4 tau rows (f32, coalesced 2KB rows)
    for (int i = tid; i < 4 * 512; i += 256) {
        int sl = i >> 9, k = i & 511;
        tauLds[sl][k] = tauG[(size_t)sample_list[g * 4 + sl] * H_ + k];
    }
    __syncthreads();

    int wv = tid >> 6, lane = tid & 63;
    int l = lane & 31, kh = lane >> 5;          // col lane, k-half
    int s = sample_list[g * 4 + wv];
    int e = cat_ids[s];
    const float* wb = W2 + ((size_t)e * 1024 + 512 + kh * 256) * H_
                      + q * 128 + l * 4;
    const float* tp = &tauLds[wv][kh * 256];

    float4 acc = {0.f, 0.f, 0.f, 0.f};
#pragma unroll 2
    for (int k4 = 0; k4 < 256; k4 += 4) {
        float4 t4 = *(const float4*)&tp[k4];                 // b128 broadcast
        float4 w0 = *(const float4*)(wb + (size_t)(k4 + 0) * H_);
        float4 w1 = *(const float4*)(wb + (size_t)(k4 + 1) * H_);
        float4 w2 = *(const float4*)(wb + (size_t)(k4 + 2) * H_);
        float4 w3 = *(const float4*)(wb + (size_t)(k4 + 3) * H_);
        acc.x = fmaf(t4.x, w0.x, acc.x); acc.y = fmaf(t4.x, w0.y, acc.y);
        acc.z = fmaf(t4.x, w0.z, acc.z); acc.w = fmaf(t4.x, w0.w, acc.w);
        acc.x = fmaf(t4.y, w1.x, acc.x); acc.y = fmaf(t4.y, w1.y, acc.y);
        acc.z = fmaf(t4.y, w1.z, acc.z); acc.w = fmaf(t4.y, w1.w, acc.w);
        acc.x = fmaf(t4.z, w2.x, acc.x); acc.y = fmaf(t4.z, w2.y, acc.y);
        acc.z = fmaf(t4.z, w2.z, acc.z); acc.w = fmaf(t4.z, w2.w, acc.w);
        acc.x = fmaf(t4.w, w3.x, acc.x); acc.y = fmaf(t4.w, w3.y, acc.y);
        acc.z = fmaf(t4.w, w3.z, acc.z); acc.w = fmaf(t4.w, w3.w, acc.w);
    }

    // fold the two k-halves: lanes l and l+32 share (sample, cols)
    acc.x += __shfl_xor(acc.x, 32, 64);
    acc.y += __shfl_xor(acc.y, 32, 64);
    acc.z += __shfl_xor(acc.z, 32, 64);
    acc.w += __shfl_xor(acc.w, 32, 64);

    if (kh == 0) {
        int n = q * 128 + l * 4;
        float4 bv = *(const float4*)(b2 + (size_t)e * H_ + n);
        float4 outv = {acc.x + bv.x, acc.y + bv.y, acc.z + bv.z, acc.w + bv.w};
        *(float4*)&bias2s[(size_t)s * H_ + n] = outv;   // coalesced 512B/wave
    }
}

// ---------------------------------------------------------------------------
// Kernels GEMM2/GEMM3: expert-grouped MFMA GEMM, K=512 (tau folded out).
// Block: 256 threads (4 waves), tile M=128 (2 samples) x N=128, BK=64.
// True 2-deep pipeline (T3+T4): raw s_barrier + counted vmcnt(8).
// Per iter: compute(t) -> s_barrier (all waves done reading buf[t&1]) ->
// stage(t+2) into buf[t&1] -> s_waitcnt vmcnt(8) (waits ONLY t+1's 8 loads;
// t+2's 8 stay in flight across the barrier) -> s_barrier -> next iter.
// Swizzle: 16B chunk c of row r at slot c^(r&7), applied on the global
// address side (gl2lds dest must be linear); frag reads conflict-free.
// ---------------------------------------------------------------------------
template <int DIN, bool PSBIAS, bool DO_SWISH, bool OUT_BF16>
__global__ __launch_bounds__(256, 2) void moe_gemm(
        const u16* __restrict__ xsrc, const u16* __restrict__ Wt,
        const float* __restrict__ bias,
        const int* __restrict__ sample_list, const int4* __restrict__ tasks,
        const int* __restrict__ itemlist, void* __restrict__ outp) {
    int item = itemlist[blockIdx.x];
    if (item < 0) return;
    int4 task = tasks[item >> 2];
    int nb = item & 3;
    int ns = task.z;
    int e = task.x;
    int s0 = sample_list[task.y];
    int s1 = (ns > 1) ? sample_list[task.y + 1] : s0;  // dup reads, masked store
    int n0 = nb * 128;

    int tid = threadIdx.x;
    int lane = tid & 63, wv = tid >> 6;          // 4 waves
    int wr = wv >> 1, wc = wv & 1;               // 2x2 wave grid
    int quad = lane >> 4, c15 = lane & 15;
    int r8 = lane >> 3, cg = lane & 7;           // staging: row-in-group, chunk

    __shared__ __align__(16) u16 xs[2][128 * 64];   // 2 x 16 KB
    __shared__ __align__(16) u16 wt[2][128 * 64];   // 2 x 16 KB

    floatx4 acc[4][4];
    floatx4 zero4 = {0.f, 0.f, 0.f, 0.f};
#pragma unroll
    for (int i = 0; i < 4; i++)
#pragma unroll
        for (int j = 0; j < 4; j++) acc[i][j] = zero4;

    const u16* wbase = Wt + (size_t)(e * H_ + n0) * DIN;
    int kc_sw = (cg ^ r8) * 8;                   // swizzled global k-offset

    auto stage = [&](int b, int k0) {            // 8 loads per wave
#pragma unroll
        for (int h = 0; h < 4; h++) {
            int rbase = h * 32 + wv * 8;         // wave-uniform row-group base
            int s = (h < 2) ? s0 : s1;
            int t = (rbase + r8) & 63;
            gl2lds16(xsrc + ((size_t)s * T_ + t) * H_ + k0 + kc_sw,
                     &xs[b][rbase * 64]);
        }
#pragma unroll
        for (int h = 0; h < 4; h++) {
            int nbase = h * 32 + wv * 8;
            gl2lds16(wbase + (size_t)(nbase + r8) * DIN + k0 + kc_sw,
                     &wt[b][nbase * 64]);
        }
    };

    auto compute = [&](int b) {
#pragma unroll
        for (int kk = 0; kk < 2; kk++) {
            int c = kk * 4 + quad;               // k-chunk index 0..7
            short8 af[4], bfr[4];
#pragma unroll
            for (int i = 0; i < 4; i++) {
                int row = wr * 64 + i * 16 + c15;
                af[i] = *(const short8*)&xs[b][row * 64 + ((c ^ (row & 7)) * 8)];
                int nr = wc * 64 + i * 16 + c15;
                bfr[i] = *(const short8*)&wt[b][nr * 64 + ((c ^ (nr & 7)) * 8)];
            }
#pragma unroll
            for (int mt = 0; mt < 4; mt++)
#pragma unroll
                for (int nt = 0; nt < 4; nt++)
                    acc[mt][nt] = __builtin_amdgcn_mfma_f32_16x16x32_bf16(
                            af[mt], bfr[nt], acc[mt][nt], 0, 0, 0);
        }
    };

    constexpr int KI = DIN / 64;                 // 8 K-iterations
    stage(0, 0);                                 // 8 loads (buf0)
    stage(1, 64);                                // 8 loads (buf1)
    asm volatile("s_waitcnt vmcnt(8)" ::: "memory");  // own buf0 loads done
    __builtin_amdgcn_s_barrier();                // all waves' buf0 done
    __builtin_amdgcn_sched_barrier(0);
#pragma unroll
    for (int t = 0; t < KI; ++t) {
        compute(t & 1);
        if (t + 1 < KI) {
            __builtin_amdgcn_s_barrier();        // all waves done reading buf[t&1]
            __builtin_amdgcn_sched_barrier(0);
            if (t + 2 < KI) {
                stage(t & 1, (t + 2) * 64);      // buf[(t+2)&1] == buf[t&1]
                asm volatile("s_waitcnt vmcnt(8)" ::: "memory"); // t+1 done
            } else {
                asm volatile("s_waitcnt vmcnt(0)" ::: "memory"); // drain last
            }
            __builtin_amdgcn_s_barrier();        // all waves' t+1 loads done
            __builtin_amdgcn_sched_barrier(0);
        }
    }

    // ---- epilogue: C/D layout col=c15, row=quad*4+r; wave-row wr = sample ----
    if (wr >= ns) return;
    int s = (wr == 0) ? s0 : s1;
    const float* bp = PSBIAS ? (bias + (size_t)s * H_)   // per-sample (GEMM2)
                             : (bias + (size_t)e * H_);  // per-expert (GEMM3)
#pragma unroll
    for (int mt = 0; mt < 4; mt++) {
        int tb = mt * 16 + quad * 4;             // t base within sample
#pragma unroll
        for (int nt = 0; nt < 4; nt++) {
            int col = n0 + wc * 64 + nt * 16 + c15;
            float bv = bp[col];
#pragma unroll
            for (int r = 0; r < 4; r++) {
                float v = acc[mt][nt][r] + bv;
                if (DO_SWISH) v = v / (1.0f + expf(-v));   // x*sigmoid(x)
                size_t oidx = ((size_t)s * T_ + tb + r) * H_ + col;
                if (OUT_BF16) ((u16*)outp)[oidx] = f2bf(v);
                else          ((float*)outp)[oidx] = v;
            }
        }
    }
}

// ---------------------------------------------------------------------------
extern "C" void kernel_launch(void* const* d_in, const int* in_sizes, int n_in,
                              void* d_out, int out_size, void* d_ws, size_t ws_size,
                              hipStream_t stream) {
    const float* actions   = (const float*)d_in[0];
    const float* timesteps = (const float*)d_in[1];
    const int*   cat_ids   = (const int*)d_in[2];
    const float* W1 = (const float*)d_in[3];
    const float* b1 = (const float*)d_in[4];
    const float* W2 = (const float*)d_in[5];
    const float* b2 = (const float*)d_in[6];
    const float* W3 = (const float*)d_in[7];
    const float* b3 = (const float*)d_in[8];

    // d_out (64 MiB) is scratch until GEMM3's epilogue:
    //   Wt2a bf16 [0,16MiB) | a_emb bf16 [16,48) | bias2s f32 [48,49) |
    //   tauG f32 [49,50).
    // ws: Wt3 bf16 [0,32MiB slot) | y bf16 [32,64) | meta.
    // GEMM3 reads only ws (+b3) and writes d_out -> no overlap hazard.
    char* ws = (char*)d_ws;
    u16* Wt3   = (u16*)ws;
    u16* y     = (u16*)(ws + (size_t)32 * 1024 * 1024);
    char* meta = ws + (size_t)64 * 1024 * 1024 + 512 * 1024;
    int*  sample_list = (int*)meta;                     // 2 KB
    int4* tasks       = (int4*)(meta + 8192);           // 272*16 B
    int*  itemlist    = (int*)(meta + 16384);           // GRID_*4 B
    int*  eoff        = (int*)(meta + 24576);           // 128 B
    int*  ecnt        = (int*)(meta + 24576 + 128);     // 128 B
    u16*  Wt2a   = (u16*)d_out;
    u16*  a_emb  = (u16*)((char*)d_out + (size_t)16 * 1024 * 1024);
    float* bias2s = (float*)((char*)d_out + (size_t)48 * 1024 * 1024);
    float* tauG   = (float*)((char*)d_out + (size_t)49 * 1024 * 1024);

    // Launch 1: embed (512 blocks) + group (block 512)
    hipLaunchKernelGGL(embed_group_kernel, dim3(B_ + 1), dim3(512), 0, stream,
                       actions, timesteps, cat_ids, W1, b1,
                       a_emb, tauG,
                       sample_list, tasks, itemlist, eoff, ecnt);
    // Launch 2: tau_bias (512 blocks) — isolated for per-dispatch counters
    hipLaunchKernelGGL(tau_bias_kernel, dim3(512), dim3(256), 0, stream,
                       W2, tauG, b2, cat_ids, sample_list, bias2s);
    // Launch 3: ct2+ct3 (1024 blocks, LDS-staged transpose)
    hipLaunchKernelGGL(ctw_kernel, dim3(1024), dim3(256), 0, stream,
                       W2, W3, Wt2a, Wt3);
    // Launch 4: GEMM2 (reads d_out scratch, writes y in ws)
    hipLaunchKernelGGL((moe_gemm<H_, true, true, true>), dim3(GRID_),
                       dim3(256), 0, stream,
                       a_emb, Wt2a, bias2s, sample_list, tasks, itemlist,
                       (void*)y);
    // Launch 5: GEMM3 (reads ws, writes d_out)
    hipLaunchKernelGGL((moe_gemm<H_, false, false, false>), dim3(GRID_),
                       dim3(256), 0, stream,
                       y, Wt3, b3, sample_list, tasks, itemlist, d_out);
}